// Round 10
// baseline (1802.354 us; speedup 1.0000x reference)
//
#include <hip/hip_runtime.h>
#include <math.h>

// ---- ws layout (u32/float offsets) ----
#define WS_CB2    0         // 192 (cb + b_hh folded for r,z)
#define WS_QE1    192       // 16384
#define WS_XE1    16576     // 65536
#define WS_G      82112     // 65536
#define WS_HW     147648    // 266240 -> ends 413888
#define WS_FW1H   413888    // 2048 u32 (8 frags)
#define WS_FWIHH  415936    // 6144 u32 (24 frags)
#define WS_FW2M   422080    // 6144
#define WS_FWHH   428224    // 6144 -> ends 434368
#define WS_GFLAG  442560    // 64 u32

// ---- dynamic LDS layout (u32 offsets) ----
#define OW2M   0        // 24 frags x 64 lanes x uint4 = 6144
#define OHROW  6144     // [8 slot][2 ks][64] uint4 = 4096
#define OGIR   10240    // [2][12][64] uint4 = 6144
#define OH32   16384    // [4][4][64] uint4 = 4096
#define OCB2   20480    // 192 f32
#define OM1F   20672    // [2][16][72] ushort = 1152 u32
#define OHF    21824    // [2][16][72] ushort = 1152 u32
#define OFLG   22976    // 4 ints: 0=fH 1=fG 2=fR 3=fC
#define LDSW   22980
#define LDSBYTES (LDSW*4)

typedef _Float16 f16x8 __attribute__((ext_vector_type(8)));
typedef float    f32x4 __attribute__((ext_vector_type(4)));
union U4H { uint4 u; f16x8 h; };
union U4F { uint4 u; f32x4 f; };
__device__ inline f16x8 TOH(uint4 u){ U4H z; z.u=u; return z.h; }
__device__ inline unsigned PKH(float a, float b){
  union{_Float16 h[2]; unsigned u;} z; z.h[0]=(_Float16)a; z.h[1]=(_Float16)b; return z.u;
}
#define MFMA(a,b,c) __builtin_amdgcn_mfma_f32_16x16x32_f16((a),(b),(c),0,0,0)
#define POLLGE(P,T) do{ while(*(volatile int*)(P) < (T)) {} asm volatile("" ::: "memory"); }while(0)

// ================= precompute =================
__global__ __launch_bounds__(256) void kPrep(
    const int* __restrict__ q, const int* __restrict__ r,
    const float* __restrict__ x_emb, const float* __restrict__ q_emb,
    const float* __restrict__ init_h, const float* __restrict__ w1,
    const float* __restrict__ b1, const float* __restrict__ w2,
    const float* __restrict__ b2, const float* __restrict__ w_ih,
    const float* __restrict__ w_hh, const float* __restrict__ b_ih,
    const float* __restrict__ b_hh,
    float* __restrict__ ws, float* __restrict__ h_full)
{
  int idx = blockIdx.x*256 + threadIdx.x;
  unsigned* wsu = (unsigned*)ws;
  if (idx < 192) {
    int g = idx; float s = b_ih[g];
    for (int j=0;j<64;j++) s += b2[j]*w_ih[g*128+j];
    if (g < 128) s += b_hh[g];          // fold b_hh for r,z gates
    ws[WS_CB2+g] = s;
  } else if (idx < 16576) {
    int e = idx-192; int c = e>>6, i = e&63;
    float s = b1[i];
    for (int k=0;k<64;k++) s += q_emb[c*64+k]*w1[(64+k)*64+i];
    ws[WS_QE1+e] = s;
  } else if (idx < 82112) {
    int e = idx-16576; int bt = e>>6, i = e&63;
    int row = q[bt] + 256*r[bt];
    float s = b1[i];
    for (int k=0;k<64;k++) s += x_emb[row*64+k]*w1[(64+k)*64+i];
    ws[WS_XE1+e] = s;
  } else if (idx < 147648) {
    int e = idx-82112; int a = e>>8, cc = e&255;
    float s = 0.f;
    for (int d=0;d<64;d++) s += q_emb[a*64+d]*q_emb[cc*64+d];
    ws[WS_G+e] = s;
  } else if (idx < 409792) {
    int e = idx-147648; int bb = e>>14, cf = e&16383;
    h_full[(size_t)bb*65*16384 + cf] = init_h[cf];
  } else if (idx < 430272) {
    // MFMA A-fragment tables (f16). frag f: mt=f>>1, ks=f&1.
    // lane: li=lane&15 (row), grp=lane>>4; word v: k = ks*32+grp*8+v*2 (+1)
    int e, tbl;
    if (idx < 411840)      { e = idx-409792; tbl=0; }
    else if (idx < 417984) { e = idx-411840; tbl=1; }
    else if (idx < 424128) { e = idx-417984; tbl=2; }
    else                   { e = idx-424128; tbl=3; }
    int f = e>>8, rem = e&255, lane = rem>>2, v = rem&3;
    int mt = f>>1, ks = f&1, li = lane&15, grp = lane>>4;
    int kg = ks*32 + grp*8 + v*2;
    float v0, v1;
    if (tbl==0){ int i = mt*16+li; v0 = w1[kg*64+i]; v1 = w1[(kg+1)*64+i];
      wsu[WS_FW1H+e] = PKH(v0,v1); }
    else if (tbl==1){ int g = mt*16+li; v0 = w_ih[g*128+64+kg]; v1 = w_ih[g*128+64+kg+1];
      wsu[WS_FWIHH+e] = PKH(v0,v1); }
    else if (tbl==2){ int g = mt*16+li; v0=0.f; v1=0.f;
      for (int j=0;j<64;j++){ float wij = w_ih[g*128+j];
        v0 += w2[kg*64+j]*wij; v1 += w2[(kg+1)*64+j]*wij; }
      wsu[WS_FW2M+e] = PKH(v0,v1); }
    else { int g = mt*16+li; v0 = w_hh[g*64+kg]; v1 = w_hh[g*64+kg+1];
      wsu[WS_FWHH+e] = PKH(v0,v1); }
  }
}

// ================= MFMA-batched wavefront =================
// 64 WGs (one chain t each, XCD-swizzled), 192 threads (3 waves), 1 WG/CU.
// W0: crit (24 whh MFMA + gates). WH: gi helper (56 MFMA). W2: I/O + staging.
__global__ __launch_bounds__(192,1) void kW(
    const int* __restrict__ q, const float* __restrict__ b_hh,
    const float* __restrict__ init_h,
    float* __restrict__ ws, float* __restrict__ h_full)
{
  extern __shared__ unsigned lds[];
  const int bid = blockIdx.x;
  const int t = ((bid&7)<<3) | (bid>>3);     // consecutive t share an XCD
  const int tid = threadIdx.x, w = tid>>6, lane = tid&63;
  const int b = lane&15, grp = lane>>4;
  unsigned* wsu = (unsigned*)ws;
  unsigned* gflag = wsu + WS_GFLAG;
  int* FLG = (int*)&lds[OFLG];

  // stage W2m frags + cb2 into LDS; zero hF
  for (int k=tid; k<6144; k+=192) lds[OW2M+k] = wsu[WS_FW2M+k];
  for (int k=tid; k<192;  k+=192) lds[OCB2+k] = wsu[WS_CB2+k];
  for (int k=tid; k<1152; k+=192) lds[OHF+k] = 0;
  if (tid<4) FLG[tid]=0;
  __syncthreads();

  if (w==0){
    // ---------------- W0: critical GRU wave ----------------
    f16x8 wf[24];
    #pragma unroll
    for (int f=0; f<24; f++){ U4H z; z.u = ((const uint4*)(wsu+WS_FWHH))[f*64+lane]; wf[f]=z.h; }
    f32x4 bh[4], hv[4];
    #pragma unroll
    for (int mt=0; mt<4; mt++){
      #pragma unroll
      for (int e=0;e<4;e++){ bh[mt][e] = b_hh[128 + mt*16 + grp*4 + e]; hv[mt][e]=0.f; }
    }
    const ushort* hfp = (const ushort*)&lds[OHF];
    ushort* hop = (ushort*)&lds[OHF];
    for (int c=0;c<256;c++){
      if ((c&3)==0) POLLGE(&FLG[3], c-3);      // h32 ring (depth 4)
      POLLGE(&FLG[1], c+1);                    // gi[c] ready
      int hbase = ((c&1)^1)*1152 + b*72;       // h(c-1) frags
      f16x8 hb0 = TOH(*(const uint4*)&hfp[hbase + grp*8]);
      f16x8 hb1 = TOH(*(const uint4*)&hfp[hbase + 32 + grp*8]);
      f32x4 acc[12];
      #pragma unroll
      for (int mt=0; mt<12; mt++){
        f32x4 a = (f32x4){0.f,0.f,0.f,0.f};
        a = MFMA(wf[mt*2],   hb0, a);
        a = MFMA(wf[mt*2+1], hb1, a);
        acc[mt] = a;
      }
      const uint4* gip = (const uint4*)&lds[OGIR + (c&1)*3072];
      uint4* h32p = (uint4*)&lds[OH32 + (c&3)*1024];
      int obase = (c&1)*1152 + b*72;
      #pragma unroll
      for (int mt=0; mt<4; mt++){
        U4F gr,gz,gn;
        gr.u = gip[mt*64+lane]; gz.u = gip[(4+mt)*64+lane]; gn.u = gip[(8+mt)*64+lane];
        f32x4 r4 = acc[mt], z4 = acc[4+mt], n4 = acc[8+mt];
        f32x4 h4 = hv[mt];
        #pragma unroll
        for (int e=0;e<4;e++){
          float rg = 1.f/(1.f+__expf(-(gr.f[e]+r4[e])));
          float zg = 1.f/(1.f+__expf(-(gz.f[e]+z4[e])));
          float xn = gn.f[e] + rg*(n4[e]+bh[mt][e]);
          float e2 = __expf(2.f*xn);
          float ng = 1.f - 2.f/(e2+1.f);
          h4[e] = zg*h4[e] + (1.f-zg)*ng;
        }
        hv[mt] = h4;
        U4F hw_; hw_.f = h4;
        h32p[mt*64+lane] = hw_.u;              // f32 row for copyout
        unsigned p0 = PKH(h4[0],h4[1]), p1 = PKH(h4[2],h4[3]);
        *(uint2*)&hop[obase + mt*16 + grp*4] = make_uint2(p0,p1);   // f16 B-frag
      }
      asm volatile("s_waitcnt lgkmcnt(0)" ::: "memory");
      if (lane==0) *(volatile int*)&FLG[0] = c+1;
    }
  } else if (w==1){
    // ---------------- WH: gi helper wave ----------------
    f16x8 w1f[8], wif[24];
    #pragma unroll
    for (int f=0; f<8; f++){ U4H z; z.u = ((const uint4*)(wsu+WS_FW1H))[f*64+lane]; w1f[f]=z.h; }
    #pragma unroll
    for (int f=0; f<24; f++){ U4H z; z.u = ((const uint4*)(wsu+WS_FWIHH))[f*64+lane]; wif[f]=z.h; }
    f32x4 xr4[4];
    #pragma unroll
    for (int mt=0; mt<4; mt++)
      #pragma unroll
      for (int e=0;e<4;e++) xr4[mt][e] = ws[WS_XE1 + (b*64+t)*64 + mt*16 + grp*4 + e];
    const int qv = q[b*64 + t];
    const uint4* hrp = (const uint4*)&lds[OHROW];
    const uint4* w2p = (const uint4*)&lds[OW2M];
    ushort* m1p = (ushort*)&lds[OM1F];
    for (int s=0; s<256; s++){
      POLLGE(&FLG[0], s-1);                    // gi ring: W0 consumed gi[s-2]
      POLLGE(&FLG[2], s+1);                    // hrow staged
      f16x8 hb0 = TOH(hrp[(s&7)*128 + lane]);
      f16x8 hb1 = TOH(hrp[(s&7)*128 + 64 + lane]);
      // m1 = relu(w1h^T @ ht_prev + e1)
      int mbase = (s&1)*1152 + b*72;
      #pragma unroll
      for (int mt=0; mt<4; mt++){
        f32x4 a = (f32x4){0.f,0.f,0.f,0.f};
        a = MFMA(w1f[mt*2],   hb0, a);
        a = MFMA(w1f[mt*2+1], hb1, a);
        const f32x4 qe = *(const f32x4*)&ws[WS_QE1 + s*64 + mt*16 + grp*4];
        f32x4 ev = (qv==s) ? xr4[mt] : qe;
        unsigned p0 = PKH(fmaxf(a[0]+ev[0],0.f), fmaxf(a[1]+ev[1],0.f));
        unsigned p1 = PKH(fmaxf(a[2]+ev[2],0.f), fmaxf(a[3]+ev[3],0.f));
        *(uint2*)&m1p[mbase + mt*16 + grp*4] = make_uint2(p0,p1);
      }
      f16x8 mb0 = TOH(*(const uint4*)&m1p[mbase + grp*8]);
      f16x8 mb1 = TOH(*(const uint4*)&m1p[mbase + 32 + grp*8]);
      uint4* gop = (uint4*)&lds[OGIR + (s&1)*3072];
      #pragma unroll
      for (int mt=0; mt<12; mt++){
        U4F cbv; cbv.u = *(const uint4*)&lds[OCB2 + mt*16 + grp*4];
        f32x4 a = cbv.f;
        a = MFMA(wif[mt*2],   hb0, a);
        a = MFMA(wif[mt*2+1], hb1, a);
        a = MFMA(TOH(w2p[(mt*2)*64+lane]),   mb0, a);
        a = MFMA(TOH(w2p[(mt*2+1)*64+lane]), mb1, a);
        U4F o; o.f = a; gop[mt*64+lane] = o.u;
      }
      asm volatile("s_waitcnt lgkmcnt(0)" ::: "memory");
      if (lane==0) *(volatile int*)&FLG[1] = s+1;
    }
  } else {
    // ---------------- W2: I/O wave (stage ht_prev + copyout + flags) ----------------
    unsigned* gfp = gflag + (t-1);
    unsigned* gfc = gflag + t;
    const size_t inbase = (size_t)(b*65 + t)*16384;   // h_full[b][t][.][.]
    uint4* hrq = (uint4*)&lds[OHROW];
    const uint4* h32q = (const uint4*)&lds[OH32];
    unsigned* hfu = (unsigned*)h_full;
    const int b2 = lane>>2, tb = lane&3;
    const size_t outbase = (size_t)(b2*65 + t + 1)*16384;
    unsigned gv = 0; int sp = 0;
    for (int c=0; c<256; c++){
      // stage rows up to c+3
      int lim = c+3; if (lim>255) lim=255;
      while (sp <= lim){
        POLLGE(&FLG[1], sp-7);                 // hrow ring depth 8
        if (t>0){
          while (gv < (unsigned)(sp+1)){
            gv = __hip_atomic_load(gfp, __ATOMIC_RELAXED, __HIP_MEMORY_SCOPE_AGENT);
            if (gv < (unsigned)(sp+1)) __builtin_amdgcn_s_sleep(1);
          }
        }
        #pragma unroll
        for (int ks=0; ks<2; ks++){
          float v[8];
          int f0 = ks*32 + grp*8;
          if (t==0){
            #pragma unroll
            for (int e=0;e<8;e++) v[e] = init_h[sp*64 + f0 + e];
          } else {
            #pragma unroll
            for (int e=0;e<8;e++){
              union{unsigned u; float f;} cv;
              cv.u = __hip_atomic_load(&hfu[inbase + sp*64 + f0 + e],
                                       __ATOMIC_RELAXED, __HIP_MEMORY_SCOPE_AGENT);
              v[e] = cv.f;
            }
          }
          uint4 o; o.x=PKH(v[0],v[1]); o.y=PKH(v[2],v[3]); o.z=PKH(v[4],v[5]); o.w=PKH(v[6],v[7]);
          hrq[(sp&7)*128 + ks*64 + lane] = o;
        }
        asm volatile("s_waitcnt lgkmcnt(0)" ::: "memory");
        if (lane==0) *(volatile int*)&FLG[2] = sp+1;
        sp++;
      }
      // copyout row c
      POLLGE(&FLG[0], c+1);
      U4F g0,g1,g2,g3;
      g0.u = h32q[(c&3)*256 + tb*64 + b2];
      g1.u = h32q[(c&3)*256 + tb*64 + b2+16];
      g2.u = h32q[(c&3)*256 + tb*64 + b2+32];
      g3.u = h32q[(c&3)*256 + tb*64 + b2+48];
      asm volatile("s_waitcnt lgkmcnt(0)" ::: "memory");
      if (lane==0) *(volatile int*)&FLG[3] = c+1;   // h32 slot free
      size_t ob = outbase + c*64 + tb*16;
      #pragma unroll
      for (int g=0; g<4; g++){
        U4F* gg = (g==0)?&g0:(g==1)?&g1:(g==2)?&g2:&g3;
        #pragma unroll
        for (int e=0;e<4;e++){
          union{float f; unsigned u;} cu; cu.f = gg->f[e];
          __hip_atomic_store(&hfu[ob + g*4 + e], cu.u,
                             __ATOMIC_RELAXED, __HIP_MEMORY_SCOPE_AGENT);
        }
      }
      asm volatile("s_waitcnt vmcnt(0)" ::: "memory");
      if (lane==0) __hip_atomic_store(gfc, (unsigned)(c+1),
                                      __ATOMIC_RELAXED, __HIP_MEMORY_SCOPE_AGENT);
    }
  }
}

// ================= hw[b][u][c] = h_full[b][u][c][:] . out_w =================
__global__ __launch_bounds__(256) void kHw(const float* __restrict__ h_full,
    const float* __restrict__ out_w, float* __restrict__ hw)
{
  __shared__ float ow[64];
  if (threadIdx.x < 64) ow[threadIdx.x] = out_w[threadIdx.x];
  __syncthreads();
  const int blk = blockIdx.x, c = threadIdx.x;
  const float* hp = h_full + ((size_t)blk*256 + c)*64;
  float s = 0.f;
  #pragma unroll
  for (int f=0; f<64; f++) s += hp[f]*ow[f];
  hw[blk*256+c] = s;
}

// ================= readout =================
__global__ __launch_bounds__(256) void kY(const int* __restrict__ q,
    const float* __restrict__ ws, const float* __restrict__ bias,
    const float* __restrict__ theta, float* __restrict__ y)
{
  const float* G  = ws + WS_G;
  const float* hw = ws + WS_HW;
  const int b = blockIdx.x >> 2, tq = blockIdx.x & 3;
  const int c = threadIdx.x;
  __shared__ float siml[64][256];
  for (int u=0; u<64; u++) {
    int qq = q[b*64+u];
    siml[u][c] = G[qq*256+c];
  }
  __syncthreads();
  const float rate = __expf(theta[0]);
  const float bv = bias[c];
  const float* hwb = hw + b*65*256;
  for (int tt=0; tt<16; tt++) {
    const int t = tq*16+tt;
    float mx = -1e30f;
    for (int u=0; u<=t; u++) {
      float s = __expf(-rate*(float)(t-u))*siml[u][c];
      mx = fmaxf(mx, s);
    }
    float se = 0.f, sw = 0.f;
    for (int u=0; u<=t; u++) {
      float s = __expf(-rate*(float)(t-u))*siml[u][c];
      float e = __expf(s-mx);
      se += e; sw += e*hwb[u*256+c];
    }
    float lg = hwb[(t+1)*256+c] + sw/se + bv;
    y[(b*64+t)*256+c] = 1.f/(1.f+__expf(-lg));
  }
}

extern "C" void kernel_launch(void* const* d_in, const int* in_sizes, int n_in,
                              void* d_out, int out_size, void* d_ws, size_t ws_size,
                              hipStream_t stream)
{
  (void)in_sizes; (void)n_in; (void)out_size; (void)ws_size;
  const int*   q      = (const int*)  d_in[0];
  const int*   r      = (const int*)  d_in[1];
  const float* x_emb  = (const float*)d_in[2];
  const float* q_emb  = (const float*)d_in[3];
  const float* init_h = (const float*)d_in[4];
  const float* w1     = (const float*)d_in[5];
  const float* b1     = (const float*)d_in[6];
  const float* w2     = (const float*)d_in[7];
  const float* b2     = (const float*)d_in[8];
  const float* w_ih   = (const float*)d_in[9];
  const float* w_hh   = (const float*)d_in[10];
  const float* b_ih   = (const float*)d_in[11];
  const float* b_hh   = (const float*)d_in[12];
  const float* bias   = (const float*)d_in[13];
  const float* out_w  = (const float*)d_in[14];
  const float* theta  = (const float*)d_in[15];

  float* out    = (float*)d_out;
  float* y      = out;
  float* h_full = out + 262144;
  float* ws     = (float*)d_ws;

  hipMemsetAsync((unsigned*)ws + WS_GFLAG, 0, 64*sizeof(unsigned), stream);
  kPrep<<<1681,256,0,stream>>>(q,r,x_emb,q_emb,init_h,w1,b1,w2,b2,w_ih,w_hh,b_ih,b_hh,ws,h_full);
  {
    hipFuncSetAttribute((const void*)kW, hipFuncAttributeMaxDynamicSharedMemorySize, LDSBYTES);
    void* ka[] = { (void*)&q, (void*)&b_hh, (void*)&init_h, (void*)&ws, (void*)&h_full };
    hipError_t e = hipLaunchCooperativeKernel((const void*)kW, dim3(64), dim3(192), ka, LDSBYTES, stream);
    if (e != hipSuccess) {
      kW<<<dim3(64),dim3(192),LDSBYTES,stream>>>(q,b_hh,init_h,ws,h_full);
    }
  }
  kHw<<<1040,256,0,stream>>>(h_full, out_w, ws + WS_HW);
  kY<<<64,256,0,stream>>>(q, ws, bias, theta, y);
}